// Round 1
// baseline (227.164 us; speedup 1.0000x reference)
//
#include <hip/hip_runtime.h>
#include <stdint.h>

typedef __bf16 bf16x8 __attribute__((ext_vector_type(8)));
typedef float  f32x4  __attribute__((ext_vector_type(4)));

static constexpr int Bn = 32, Cn = 128, Hn = 64, Wn = 64, HWn = 4096;
static constexpr size_t OFF_XT    = 0;                       // 33,554,432 B (bf16 x, chunk-major NHWC)
static constexpr size_t OFF_WF    = 33554432;                // 221,184 B (B-fragment-ordered weights)
static constexpr size_t OFF_IDX   = 33775616;                // 1,536 B
static constexpr size_t OFF_M     = 33777152;                // 33,554,432 B (median result, bf16, NCHW)
static constexpr size_t OFF_STATS = 67331584;                // 1,024 B
static constexpr size_t OFF_BN    = 67332608;                // 1,024 B

__device__ __forceinline__ unsigned short f32_to_bf16(float f) {
    union { float f; unsigned u; } v; v.f = f;
    unsigned u = v.u;
    return (unsigned short)((u + 0x7FFFu + ((u >> 16) & 1u)) >> 16);
}
__device__ __forceinline__ float bf16_to_f32(unsigned short h) {
    union { unsigned u; float f; } v; v.u = ((unsigned)h) << 16;
    return v.f;
}

// ---- K0: x NCHW fp32 -> xT[b][q][y][x][32ci] bf16 (chunk-major NHWC) ----
__global__ __launch_bounds__(256) void k_transpose(const float* __restrict__ x,
                                                   unsigned short* __restrict__ xT) {
    __shared__ __align__(16) unsigned short sm[256 * 40];
    int blk = blockIdx.x;                 // b*64 + q*16 + pt
    int pt = blk & 15, q = (blk >> 4) & 3, b = blk >> 6;
    int p0 = pt * 256;
    int t = threadIdx.x;
    const float* xp = x + ((size_t)(b * Cn + q * 32) * HWn) + p0 + t;
#pragma unroll
    for (int cil = 0; cil < 32; ++cil)
        sm[t * 40 + cil] = f32_to_bf16(xp[(size_t)cil * HWn]);
    __syncthreads();
    uint4* dst = (uint4*)(xT + ((size_t)(b * 4 + q) * HWn + p0) * 32);
#pragma unroll
    for (int pass = 0; pass < 4; ++pass) {
        int pix = pass * 64 + (t >> 2);
        int ch  = t & 3;
        dst[pix * 4 + ch] = *(const uint4*)(&sm[pix * 40 + ch * 8]);
    }
}

// ---- K1a: recover idx[j][c] from one-hot hs (3,32,128) ----
__global__ void k_idx(const float* __restrict__ hs, int* __restrict__ idx) {
    int t = blockIdx.x * 256 + threadIdx.x;
    if (t >= 384) return;
    int j = t >> 7, c = t & 127;
    int found = 0;
    for (int d = 0; d < 32; ++d)
        if (hs[(j * 32 + d) * 128 + c] > 0.5f) found = d;
    idx[t] = found;
}

// ---- K1b: sketched weights in MFMA B-fragment order ----
// layout: f = ((q*9+t)*6+nt)*512 + lane*8 + jj holds B[k=(lane>>4)*8+jj][n=nt*16+(lane&15)]
// where k = ci within chunk q, n = j*32+d output channel, t = kh*3+kw
__global__ __launch_bounds__(256) void k_wsk(const float* __restrict__ w2,
                                             const float* __restrict__ hs,
                                             const float* __restrict__ ss,
                                             unsigned short* __restrict__ wf) {
    int f = blockIdx.x * 256 + threadIdx.x;   // 110592 total
    int jj   = f & 7;
    int lane = (f >> 3) & 63;
    int nt   = (f >> 9) % 6;
    int qt   = f / (512 * 6);
    int t    = qt % 9;
    int q    = qt / 9;
    int k  = ((lane >> 4) << 3) + jj;
    int ci = q * 32 + k;
    int n  = nt * 16 + (lane & 15);
    int j = n >> 5, d = n & 31;
    float sum = 0.f;
    for (int c = 0; c < 128; ++c) {
        float g = hs[(j * 32 + d) * 128 + c];
        if (g != 0.f) sum += g * ss[j * 128 + c] * w2[(c * 128 + ci) * 9 + t];
    }
    wf[f] = f32_to_bf16(sum);
}

// ---- K2: conv(96ch) + unsketch + median3 -> m (bf16, NCHW) ----
// grid 512 = b*16 + tile; tile = 4 rows x 64 cols; wave w owns row py=w.
__global__ __launch_bounds__(256, 2) void k_conv(const unsigned short* __restrict__ xT,
                                                 const unsigned short* __restrict__ wf,
                                                 const int* __restrict__ idx,
                                                 const float* __restrict__ ss,
                                                 unsigned short* __restrict__ m_out) {
    __shared__ __align__(16) unsigned short sm[25088];  // staging (15840) aliased with y (256*98)
    __shared__ int   idx_sh[384];
    __shared__ float ss_sh[384];
    int tid  = threadIdx.x;
    int blk  = blockIdx.x;
    int tile = blk & 15, b = blk >> 4;
    int ty0  = tile * 4;
    int wv   = tid >> 6, lane = tid & 63;
    int quad = lane >> 4, l15 = lane & 15;

    for (int i = tid; i < 384; i += 256) { idx_sh[i] = idx[i]; ss_sh[i] = ss[i]; }

    f32x4 acc[4][6];
#pragma unroll
    for (int a = 0; a < 4; ++a)
#pragma unroll
        for (int nb = 0; nb < 6; ++nb) acc[a][nb] = (f32x4){0.f, 0.f, 0.f, 0.f};

    const unsigned short* wl = wf + lane * 8;

    for (int q = 0; q < 4; ++q) {
        __syncthreads();
        // stage halo: 396 records (6 rows x 66 cols) of 32 ci (64 B each)
#pragma unroll
        for (int pass = 0; pass < 2; ++pass) {
            int r = tid + pass * 256;
            if (r < 396) {
                int hy = r / 66, hx = r - hy * 66;
                int gy = ty0 + hy - 1, gx = hx - 1;
                uint4* dst = (uint4*)(&sm[r * 40]);
                if (gy >= 0 && gy < 64 && gx >= 0 && gx < 64) {
                    const uint4* src = (const uint4*)(xT + ((size_t)(b * 4 + q) * HWn + gy * 64 + gx) * 32);
                    dst[0] = src[0]; dst[1] = src[1]; dst[2] = src[2]; dst[3] = src[3];
                } else {
                    uint4 z = {0u, 0u, 0u, 0u};
                    dst[0] = z; dst[1] = z; dst[2] = z; dst[3] = z;
                }
            }
        }
        __syncthreads();
#pragma unroll
        for (int tp = 0; tp < 9; ++tp) {
            int dy = tp / 3, dx = tp % 3;
            bf16x8 afr[4];
#pragma unroll
            for (int mq = 0; mq < 4; ++mq) {
                int off = ((wv + dy) * 66 + mq * 16 + l15 + dx) * 40 + quad * 8;
                afr[mq] = *(const bf16x8*)(&sm[off]);
            }
            bf16x8 bfr[6];
            const unsigned short* wb = wl + (size_t)((q * 9 + tp) * 6) * 512;
#pragma unroll
            for (int nb = 0; nb < 6; ++nb)
                bfr[nb] = *(const bf16x8*)(wb + nb * 512);
#pragma unroll
            for (int mq = 0; mq < 4; ++mq)
#pragma unroll
                for (int nb = 0; nb < 6; ++nb)
                    acc[mq][nb] = __builtin_amdgcn_mfma_f32_16x16x32_bf16(afr[mq], bfr[nb], acc[mq][nb], 0, 0, 0);
        }
    }
    __syncthreads();
    // dump y tile to LDS: pixel p in [0,256), channel in [0,96), stride 98
#pragma unroll
    for (int mq = 0; mq < 4; ++mq) {
#pragma unroll
        for (int nb = 0; nb < 6; ++nb) {
            int ch = nb * 16 + l15;
            int pbase = wv * 64 + mq * 16 + quad * 4;
#pragma unroll
            for (int r = 0; r < 4; ++r)
                sm[(pbase + r) * 98 + ch] = f32_to_bf16(acc[mq][nb][r]);
        }
    }
    __syncthreads();
    // unsketch + median-of-3 + write m (coalesced: 64 lanes -> 128 contiguous bytes)
    int p = tid;
    unsigned short* mp = m_out + (size_t)b * Cn * HWn + tile * 256 + tid;
#pragma unroll 4
    for (int c = 0; c < 128; ++c) {
        int i0 = idx_sh[c], i1 = idx_sh[128 + c], i2 = idx_sh[256 + c];
        float z0 = ss_sh[c]       * bf16_to_f32(sm[p * 98 + i0]);
        float z1 = ss_sh[128 + c] * bf16_to_f32(sm[p * 98 + 32 + i1]);
        float z2 = ss_sh[256 + c] * bf16_to_f32(sm[p * 98 + 64 + i2]);
        float lo = fminf(z0, z1), hi = fmaxf(z0, z1);
        float med = fmaxf(lo, fminf(hi, z2));
        mp[(size_t)c * HWn] = f32_to_bf16(med);
    }
}

// ---- K3a: per-channel sum / sumsq of m ----
__global__ __launch_bounds__(256) void k_stats(const unsigned short* __restrict__ m,
                                               float* __restrict__ stats) {
    int blk = blockIdx.x;            // c*4 + bq
    int c = blk >> 2, bq = blk & 3;
    int tid = threadIdx.x;
    float s = 0.f, s2 = 0.f;
    for (int b = bq * 8; b < bq * 8 + 8; ++b) {
        const ushort4* mp = (const ushort4*)(m + (size_t)(b * Cn + c) * HWn);
#pragma unroll
        for (int i = 0; i < 4; ++i) {
            ushort4 v = mp[i * 256 + tid];
            float a0 = bf16_to_f32(v.x), a1 = bf16_to_f32(v.y);
            float a2 = bf16_to_f32(v.z), a3 = bf16_to_f32(v.w);
            s  += a0 + a1 + a2 + a3;
            s2 += a0 * a0 + a1 * a1 + a2 * a2 + a3 * a3;
        }
    }
    for (int o = 32; o > 0; o >>= 1) { s += __shfl_down(s, o); s2 += __shfl_down(s2, o); }
    __shared__ float rs[8];
    if ((tid & 63) == 0) { rs[tid >> 6] = s; rs[4 + (tid >> 6)] = s2; }
    __syncthreads();
    if (tid == 0) {
        float S = rs[0] + rs[1] + rs[2] + rs[3];
        float S2 = rs[4] + rs[5] + rs[6] + rs[7];
        atomicAdd(&stats[c], S);
        atomicAdd(&stats[128 + c], S2);
    }
}

// ---- K3b: finalize BN coefficients ----
__global__ void k_bn(const float* __restrict__ stats, const float* __restrict__ gamma,
                     const float* __restrict__ beta, float* __restrict__ bn) {
    int c = threadIdx.x;
    if (c < 128) {
        const float N = 131072.f;
        float mean = stats[c] / N;
        float var  = stats[128 + c] / N - mean * mean;
        float sc   = gamma[c] * rsqrtf(var + 1e-5f);
        bn[c] = sc;
        bn[128 + c] = beta[c] - mean * sc;
    }
}

// ---- K4: out = relu(m*sc+sh) + x ----
__global__ __launch_bounds__(256) void k_apply(const unsigned short* __restrict__ m,
                                               const float* __restrict__ x,
                                               const float* __restrict__ bn,
                                               float* __restrict__ out) {
    int i4 = blockIdx.x * 256 + threadIdx.x;      // 4,194,304 groups of 4
    size_t base = (size_t)i4 * 4;
    int c = (int)((base >> 12) & 127);
    float sc = bn[c], sh = bn[128 + c];
    ushort4 mv = ((const ushort4*)m)[i4];
    float4  xv = ((const float4*)x)[i4];
    float4 o;
    o.x = fmaxf(bf16_to_f32(mv.x) * sc + sh, 0.f) + xv.x;
    o.y = fmaxf(bf16_to_f32(mv.y) * sc + sh, 0.f) + xv.y;
    o.z = fmaxf(bf16_to_f32(mv.z) * sc + sh, 0.f) + xv.z;
    o.w = fmaxf(bf16_to_f32(mv.w) * sc + sh, 0.f) + xv.w;
    ((float4*)out)[i4] = o;
}

extern "C" void kernel_launch(void* const* d_in, const int* in_sizes, int n_in,
                              void* d_out, int out_size, void* d_ws, size_t ws_size,
                              hipStream_t stream) {
    const float* x      = (const float*)d_in[0];
    // d_in[1] = w1, d_in[3] = gamma1, d_in[4] = beta1 : dead code in the reference
    const float* w2     = (const float*)d_in[2];
    const float* gamma2 = (const float*)d_in[5];
    const float* beta2  = (const float*)d_in[6];
    const float* hs     = (const float*)d_in[7];
    const float* ss     = (const float*)d_in[8];
    float* out = (float*)d_out;

    char* ws = (char*)d_ws;
    unsigned short* xT  = (unsigned short*)(ws + OFF_XT);
    unsigned short* wfp = (unsigned short*)(ws + OFF_WF);
    int*            idp = (int*)(ws + OFF_IDX);
    unsigned short* mp  = (unsigned short*)(ws + OFF_M);
    float*          st  = (float*)(ws + OFF_STATS);
    float*          bnp = (float*)(ws + OFF_BN);

    hipMemsetAsync(st, 0, 1024, stream);
    k_transpose<<<2048, 256, 0, stream>>>(x, xT);
    k_idx<<<2, 256, 0, stream>>>(hs, idp);
    k_wsk<<<432, 256, 0, stream>>>(w2, hs, ss, wfp);
    k_conv<<<512, 256, 0, stream>>>(xT, wfp, idp, ss, mp);
    k_stats<<<512, 256, 0, stream>>>(mp, st);
    k_bn<<<1, 128, 0, stream>>>(st, gamma2, beta2, bnp);
    k_apply<<<16384, 256, 0, stream>>>(mp, x, bnp, out);
}